// Round 3
// baseline (203.006 us; speedup 1.0000x reference)
//
#include <hip/hip_runtime.h>
#include <hip/hip_bf16.h>
#include <stdint.h>

// KAN layer fused kernel, MI355X (gfx950). R3: latency-bound fix.
// out[M=65536, N=256] (fp32) = A[M,K=256] @ W^T
//   A[m,k] = c0[k]*B0(tanh(x[m,k])) + c1[k]*B1(tanh(x[m,k]))  (on the fly -> bf16)
//   W = outer_coeffs [N,K] fp32 -> bf16 (pre-kernel into d_ws, L2-resident)
// R2 was barrier/latency-bound (HBM 24%, VALU 31%, MFMA 6%): __syncthreads drains
// vmcnt(0) so no load ever crossed an iteration. R3: B direct from global (no LDS),
// A double-buffered with raw s_barrier + lgkmcnt-only wait, x prefetched 2 chunks ahead.

typedef __attribute__((ext_vector_type(8))) short short8;   // 8 bf16 (MFMA A/B frag)
typedef __attribute__((ext_vector_type(4))) float f32x4;    // MFMA C/D frag

__device__ __forceinline__ uint16_t f2bf(float f) {
    union { float f; uint32_t u; } v; v.f = f;
    uint32_t r = v.u + 0x7FFFu + ((v.u >> 16) & 1u);  // RNE
    return (uint16_t)(r >> 16);
}

__device__ __forceinline__ float cube_relu(float v) {
    float m = fmaxf(v, 0.0f);
    return m * m * m;
}

__device__ __forceinline__ float inner_eval(float xx, float c0, float c1) {
    float e  = __expf(2.0f * xx);                       // tanh = 1 - 2/(e^{2x}+1)
    float t  = 1.0f - 2.0f * __builtin_amdgcn_rcpf(e + 1.0f);
    float u  = (t + 1.0f) * 3.5f;                       // in [0,7]
    float w0 = cube_relu(u);
    float w1 = cube_relu(u - 1.0f);
    float w2 = cube_relu(u - 2.0f);
    float w3 = cube_relu(u - 3.0f);
    float w4 = cube_relu(u - 4.0f);
    float w5 = cube_relu(u - 5.0f);
    float B0 = w0 - 4.0f*w1 + 6.0f*w2 - 4.0f*w3 + w4;
    float B1 = w1 - 4.0f*w2 + 6.0f*w3 - 4.0f*w4 + w5;
    return (c0 * B0 + c1 * B1) * (1.0f / 6.0f);
}

// barrier that does NOT drain vmcnt: wait lgkmcnt(0) only (imm: vmcnt=63, expcnt=7, lgkm=0)
#define LGKM_BARRIER() do { \
    __asm__ volatile("" ::: "memory"); \
    __builtin_amdgcn_s_waitcnt(0xC07F); \
    __builtin_amdgcn_s_barrier(); \
    __asm__ volatile("" ::: "memory"); \
} while (0)

// W fp32 -> bf16, 65536 elems, 4/thread
__global__ void conv_w(const float4* __restrict__ wf, uint2* __restrict__ o) {
    const int i = blockIdx.x * blockDim.x + threadIdx.x;  // 0..16383
    const float4 v = wf[i];
    uint2 r;
    r.x = (uint32_t)f2bf(v.x) | ((uint32_t)f2bf(v.y) << 16);
    r.y = (uint32_t)f2bf(v.z) | ((uint32_t)f2bf(v.w) << 16);
    o[i] = r;
}

// Block: 256 threads (4 waves). BM=64, BN=256 (wave w: n in [w*64, w*64+64)), BK=32, 8 iters.
// LDS: A0 [64][32] bf16 @0 | A1 @4096 | C2 float2[256] @8192 -> 10 KB total.
#define SMEM_BYTES 10240

__global__ void kan_fused(const float* __restrict__ x,
                          const float* __restrict__ ic,
                          const uint16_t* __restrict__ wb,
                          float* __restrict__ out)
{
    __shared__ __align__(16) char smem[SMEM_BYTES];
    float2* C2 = (float2*)(smem + 8192);

    const int t    = threadIdx.x;
    const int lane = t & 63;
    const int w    = t >> 6;
    const int m0   = blockIdx.x * 64;
    const int rowA = t >> 3;          // 0..31
    const int colA = (t & 7) << 2;    // 0..28 step 4
    const int mrow = lane & 15;
    const int quad = lane >> 4;

    // coeff preload (blockDim == IN == 256)
    C2[t] = make_float2(ic[t * 5 + 0], ic[t * 5 + 1]);

    // x addressing: thread stages rows rowA, rowA+32 at cols [chunk*32+colA .. +4)
    const float* xp0 = x + (size_t)(m0 + rowA) * 256 + colA;
    const float* xp1 = xp0 + 32 * 256;

    // prefetch chunk 0 (in flight across the C2 barrier)
    float4 xv0 = *(const float4*)(xp0);
    float4 xv1 = *(const float4*)(xp1);

    f32x4 acc[4][4];
    #pragma unroll
    for (int i = 0; i < 4; ++i)
        #pragma unroll
        for (int j = 0; j < 4; ++j)
            acc[i][j] = (f32x4){0.f, 0.f, 0.f, 0.f};

    LGKM_BARRIER();   // C2 visible

    // stage chunk 0 into buf0
    {
        const int gk = colA;
        const float4 cA = *(const float4*)(&C2[gk]);
        const float4 cB = *(const float4*)(&C2[gk + 2]);
        uint32_t p0 = (uint32_t)f2bf(inner_eval(xv0.x, cA.x, cA.y)) |
                      ((uint32_t)f2bf(inner_eval(xv0.y, cA.z, cA.w)) << 16);
        uint32_t p1 = (uint32_t)f2bf(inner_eval(xv0.z, cB.x, cB.y)) |
                      ((uint32_t)f2bf(inner_eval(xv0.w, cB.z, cB.w)) << 16);
        *(uint2*)(smem + (rowA * 32 + colA) * 2) = make_uint2(p0, p1);
        uint32_t q0 = (uint32_t)f2bf(inner_eval(xv1.x, cA.x, cA.y)) |
                      ((uint32_t)f2bf(inner_eval(xv1.y, cA.z, cA.w)) << 16);
        uint32_t q1 = (uint32_t)f2bf(inner_eval(xv1.z, cB.x, cB.y)) |
                      ((uint32_t)f2bf(inner_eval(xv1.w, cB.z, cB.w)) << 16);
        *(uint2*)(smem + ((rowA + 32) * 32 + colA) * 2) = make_uint2(q0, q1);
    }
    // prefetch chunk 1
    xv0 = *(const float4*)(xp0 + 32);
    xv1 = *(const float4*)(xp1 + 32);

    #pragma unroll 1
    for (int kk = 0; kk < 8; ++kk) {
        const int p = kk & 1;

        // B frags from global (L2-hot) — issued BEFORE the barrier, stay in flight across it
        short8 bfrag[4];
        #pragma unroll
        for (int j = 0; j < 4; ++j)
            bfrag[j] = *(const short8*)(wb + (w * 64 + j * 16 + mrow) * 256 + kk * 32 + quad * 8);

        LGKM_BARRIER();   // prev iter's ds_writes visible; vm loads NOT drained

        // A frags for chunk kk from buf[p]
        short8 afrag[4];
        const uint16_t* Ab = (const uint16_t*)(smem + p * 4096);
        #pragma unroll
        for (int i = 0; i < 4; ++i)
            afrag[i] = *(const short8*)(Ab + (i * 16 + mrow) * 32 + quad * 8);

        // stage chunk kk+1 into buf[p^1]; prefetch chunk kk+2
        if (kk < 7) {
            const float4 xc0 = xv0, xc1 = xv1;
            if (kk < 6) {
                xv0 = *(const float4*)(xp0 + (kk + 2) * 32);
                xv1 = *(const float4*)(xp1 + (kk + 2) * 32);
            }
            const int gk = (kk + 1) * 32 + colA;
            const float4 cA = *(const float4*)(&C2[gk]);
            const float4 cB = *(const float4*)(&C2[gk + 2]);
            char* Aw = smem + (p ^ 1) * 4096;
            uint32_t p0 = (uint32_t)f2bf(inner_eval(xc0.x, cA.x, cA.y)) |
                          ((uint32_t)f2bf(inner_eval(xc0.y, cA.z, cA.w)) << 16);
            uint32_t p1 = (uint32_t)f2bf(inner_eval(xc0.z, cB.x, cB.y)) |
                          ((uint32_t)f2bf(inner_eval(xc0.w, cB.z, cB.w)) << 16);
            *(uint2*)(Aw + (rowA * 32 + colA) * 2) = make_uint2(p0, p1);
            uint32_t q0 = (uint32_t)f2bf(inner_eval(xc1.x, cA.x, cA.y)) |
                          ((uint32_t)f2bf(inner_eval(xc1.y, cA.z, cA.w)) << 16);
            uint32_t q1 = (uint32_t)f2bf(inner_eval(xc1.z, cB.x, cB.y)) |
                          ((uint32_t)f2bf(inner_eval(xc1.w, cB.z, cB.w)) << 16);
            *(uint2*)(Aw + ((rowA + 32) * 32 + colA) * 2) = make_uint2(q0, q1);
        }

        // MFMA (waits: lgkm for afrag, vmcnt for bfrag — fine-grained, compiler-inserted)
        #pragma unroll
        for (int i = 0; i < 4; ++i)
            #pragma unroll
            for (int j = 0; j < 4; ++j)
                acc[i][j] = __builtin_amdgcn_mfma_f32_16x16x32_bf16(afrag[i], bfrag[j], acc[i][j], 0, 0, 0);
    }

    // epilogue: direct fp32 stores. C/D layout: col=lane&15, row=quad*4+reg.
    // For fixed (i,j,r): each quad writes 64 contiguous bytes — fully covered segments.
    #pragma unroll
    for (int i = 0; i < 4; ++i) {
        #pragma unroll
        for (int r = 0; r < 4; ++r) {
            const size_t row = (size_t)(m0 + i * 16 + quad * 4 + r);
            float* orow = out + row * 256 + w * 64 + mrow;
            #pragma unroll
            for (int j = 0; j < 4; ++j)
                orow[j * 16] = acc[i][j][r];
        }
    }
}

extern "C" void kernel_launch(void* const* d_in, const int* in_sizes, int n_in,
                              void* d_out, int out_size, void* d_ws, size_t ws_size,
                              hipStream_t stream) {
    const float* x  = (const float*)d_in[0];   // [16,4096,256] fp32
    const float* ic = (const float*)d_in[1];   // [256,5] fp32
    const float* oc = (const float*)d_in[2];   // [256,256] fp32
    uint16_t* wb = (uint16_t*)d_ws;            // 128 KB bf16 copy of W

    conv_w<<<64, 256, 0, stream>>>((const float4*)oc, (uint2*)wb);
    kan_fused<<<1024, 256, 0, stream>>>(x, ic, wb, (float*)d_out);
}